// Round 4
// baseline (134.688 us; speedup 1.0000x reference)
//
#include <hip/hip_runtime.h>
#include <math.h>

#define NFILT 64
#define FRAME_LEN 400
#define FRAME_STEP 160
#define WMAX 24            // max nonzero span of one mel filter (verified R1-R3)
#define WSTRIDE 25         // gcd(25,32)=1 -> conflict-free lane-indexed LDS reads
#define WAVES 4
#define NBLOCKS 1024       // 4096 waves, all resident at >=4 waves/SIMD
#define PWBINS 280         // 257 bins + pad so the mel window can overrun safely

// ---- load one 400-sample frame (8 samples/lane in lanes 0..49) + pre-emphasis ----
__device__ __forceinline__ void load_pre(const float* __restrict__ x, long base,
                                         int l, bool valid, float (&v)[8]) {
    float a0=0,a1=0,a2=0,a3=0,a4=0,a5=0,a6=0,a7=0;
    if (valid && l < 50) {
        const float4* p4 = reinterpret_cast<const float4*>(x + base + 8 * l);
        float4 A = p4[0], B = p4[1];
        a0=A.x; a1=A.y; a2=A.z; a3=A.w; a4=B.x; a5=B.y; a6=B.z; a7=B.w;
    }
    float edge = 0.0f;
    if (valid && base > 0) edge = x[base - 1];   // pre[0] of audio = x[0] - 0.97*0
    float prev = __shfl_up(a7, 1, 64);
    if (l == 0) prev = edge;
    const bool act = valid && (l < 50);
    v[0] = act ? fmaf(-0.97f, prev, a0) : 0.0f;
    v[1] = act ? fmaf(-0.97f, a0, a1) : 0.0f;
    v[2] = act ? fmaf(-0.97f, a1, a2) : 0.0f;
    v[3] = act ? fmaf(-0.97f, a2, a3) : 0.0f;
    v[4] = act ? fmaf(-0.97f, a3, a4) : 0.0f;
    v[5] = act ? fmaf(-0.97f, a4, a5) : 0.0f;
    v[6] = act ? fmaf(-0.97f, a5, a6) : 0.0f;
    v[7] = act ? fmaf(-0.97f, a6, a7) : 0.0f;
}

// ---- 512-pt FFT: 6 cross-lane shuffle stages + W512 twiddle + in-reg radix-8 ----
__device__ __forceinline__ void fft512(float (&vr)[8], float (&vi)[8],
                                       const float (&cA)[6], const float (&sA)[6],
                                       const float (&sg)[6],
                                       const float (&br)[8], const float (&bi)[8]) {
#pragma unroll
    for (int j = 0; j < 6; j++) {
        const int d = 32 >> j;
        const float c = cA[j], s = sA[j], g = sg[j];
#pragma unroll
        for (int r = 0; r < 8; r++) {
            float pr = __shfl_xor(vr[r], d, 64);
            float pi = __shfl_xor(vi[r], d, 64);
            float tr = fmaf(g, vr[r], pr);
            float ti = fmaf(g, vi[r], pi);
            vr[r] = tr * c - ti * s;
            vi[r] = tr * s + ti * c;
        }
    }
#pragma unroll
    for (int r = 1; r < 8; r++) {
        float tr = vr[r], ti = vi[r];
        vr[r] = tr * br[r] - ti * bi[r];
        vi[r] = tr * bi[r] + ti * br[r];
    }
    const float RH = 0.70710678118654752f;
    {
        float t0r=vr[0]+vr[4], t0i=vi[0]+vi[4];
        float d0r=vr[0]-vr[4], d0i=vi[0]-vi[4];
        float t1r=vr[1]+vr[5], t1i=vi[1]+vi[5];
        float d1r=vr[1]-vr[5], d1i=vi[1]-vi[5];
        float t2r=vr[2]+vr[6], t2i=vi[2]+vi[6];
        float d2r=vr[2]-vr[6], d2i=vi[2]-vi[6];
        float t3r=vr[3]+vr[7], t3i=vi[3]+vi[7];
        float d3r=vr[3]-vr[7], d3i=vi[3]-vi[7];
        vr[0]=t0r; vi[0]=t0i; vr[1]=t1r; vi[1]=t1i;
        vr[2]=t2r; vi[2]=t2i; vr[3]=t3r; vi[3]=t3i;
        vr[4]=d0r;                 vi[4]=d0i;
        vr[5]=(d1r+d1i)*RH;        vi[5]=(d1i-d1r)*RH;
        vr[6]=d2i;                 vi[6]=-d2r;
        vr[7]=(d3i-d3r)*RH;        vi[7]=-(d3r+d3i)*RH;
    }
    {
        float t0r=vr[0]+vr[2], t0i=vi[0]+vi[2];
        float d0r=vr[0]-vr[2], d0i=vi[0]-vi[2];
        float t1r=vr[1]+vr[3], t1i=vi[1]+vi[3];
        float d1r=vr[1]-vr[3], d1i=vi[1]-vi[3];
        vr[0]=t0r; vi[0]=t0i; vr[1]=t1r; vi[1]=t1i;
        vr[2]=d0r; vi[2]=d0i; vr[3]=d1i; vi[3]=-d1r;
        float t4r=vr[4]+vr[6], t4i=vi[4]+vi[6];
        float d4r=vr[4]-vr[6], d4i=vi[4]-vi[6];
        float t5r=vr[5]+vr[7], t5i=vi[5]+vi[7];
        float d5r=vr[5]-vr[7], d5i=vi[5]-vi[7];
        vr[4]=t4r; vi[4]=t4i; vr[5]=t5r; vi[5]=t5i;
        vr[6]=d4r; vi[6]=d4i; vr[7]=d5i; vi[7]=-d5r;
    }
    {
        float t0r=vr[0]+vr[1], t0i=vi[0]+vi[1];
        float d0r=vr[0]-vr[1], d0i=vi[0]-vi[1];
        vr[0]=t0r; vi[0]=t0i; vr[1]=d0r; vi[1]=d0i;
        float t2r=vr[2]+vr[3], t2i=vi[2]+vi[3];
        float d2r=vr[2]-vr[3], d2i=vi[2]-vi[3];
        vr[2]=t2r; vi[2]=t2i; vr[3]=d2r; vi[3]=d2i;
        float t4r=vr[4]+vr[5], t4i=vi[4]+vi[5];
        float d4r=vr[4]-vr[5], d4i=vi[4]-vi[5];
        vr[4]=t4r; vi[4]=t4i; vr[5]=d4r; vi[5]=d4i;
        float t6r=vr[6]+vr[7], t6i=vi[6]+vi[7];
        float d6r=vr[6]-vr[7], d6i=vi[6]-vi[7];
        vr[6]=t6r; vi[6]=t6i; vr[7]=d6r; vi[7]=d6i;
    }
}

// ---- conj-symmetry untangle (z = a + i b) + power spectrum -> LDS ----
__device__ __forceinline__ void untangle_power(const float (&vr)[8], const float (&vi)[8],
                                               int l, int rl, int Lp,
                                               float* __restrict__ pwrow) {
    float c0r = __shfl(vr[7], Lp, 64), c0i = __shfl(vi[7], Lp, 64);  // p=0
    float c1r = __shfl(vr[3], Lp, 64), c1i = __shfl(vi[3], Lp, 64);  // p=4
    float c2r = __shfl(vr[5], Lp, 64), c2i = __shfl(vi[5], Lp, 64);  // p=2
    float c3r = __shfl(vr[1], Lp, 64), c3i = __shfl(vi[1], Lp, 64);  // p=6
    if (l == 0) {
        c0r = vr[0]; c0i = vi[0];
        c1r = vr[7]; c1i = vi[7];
        c2r = vr[3]; c2i = vi[3];
        c3r = vr[5]; c3i = vi[5];
    }
    const float S4 = (1.0f / 512.0f) * 0.25f;
    {
        float zr = vr[0], zi = vi[0];
        float e1 = zr + c0r, e2 = zi - c0i, o1 = zi + c0i, o2 = c0r - zr;
        *reinterpret_cast<float2*>(&pwrow[2 * rl]) =
            make_float2((e1*e1 + e2*e2) * S4, (o1*o1 + o2*o2) * S4);
    }
    {
        float zr = vr[4], zi = vi[4];
        float e1 = zr + c1r, e2 = zi - c1i, o1 = zi + c1i, o2 = c1r - zr;
        *reinterpret_cast<float2*>(&pwrow[2 * (rl + 64)]) =
            make_float2((e1*e1 + e2*e2) * S4, (o1*o1 + o2*o2) * S4);
    }
    {
        float zr = vr[2], zi = vi[2];
        float e1 = zr + c2r, e2 = zi - c2i, o1 = zi + c2i, o2 = c2r - zr;
        *reinterpret_cast<float2*>(&pwrow[2 * (rl + 128)]) =
            make_float2((e1*e1 + e2*e2) * S4, (o1*o1 + o2*o2) * S4);
    }
    {
        float zr = vr[6], zi = vi[6];
        float e1 = zr + c3r, e2 = zi - c3i, o1 = zi + c3i, o2 = c3r - zr;
        *reinterpret_cast<float2*>(&pwrow[2 * (rl + 192)]) =
            make_float2((e1*e1 + e2*e2) * S4, (o1*o1 + o2*o2) * S4);
    }
    if (l == 0) {   // bin 256 pairs with itself: Xa=Re(Z[256]), Xb=Im(Z[256])
        pwrow[512] = vr[1] * vr[1] * (1.0f / 512.0f);
        pwrow[513] = vi[1] * vi[1] * (1.0f / 512.0f);
    }
}

__global__ __launch_bounds__(256, 4) void fbank_kernel(const float* __restrict__ x,
                                                       const float* __restrict__ filters,
                                                       float* __restrict__ out,
                                                       int num_frames) {
    __shared__ float wc_lds[NFILT * WSTRIDE];
    __shared__ int   lo_lds[NFILT];
    __shared__ float pw[WAVES][2][PWBINS * 2];   // [wave][pair][(pa,pb) per bin]

    const int t = threadIdx.x;
    const int l = t & 63;
    const int w = t >> 6;
    float* pwA = pw[w][0];
    float* pwB = pw[w][1];

    // zero pad bins [257, PWBINS) once
    if (l < 2 * (PWBINS - 257)) {
        pwA[2 * 257 + l] = 0.0f;
        pwB[2 * 257 + l] = 0.0f;
    }

    // ---- wave 0: batched, pipelineable filter-window scan (no serial-load chain) ----
    if (w == 0) {
        int lo = 257;
#pragma unroll 4
        for (int k0 = 0; k0 < 264; k0 += 8) {
            float fv[8];
#pragma unroll
            for (int i = 0; i < 8; i++) {
                int k = k0 + i;
                fv[i] = (k < 257) ? filters[k * NFILT + l] : 0.0f;
            }
#pragma unroll
            for (int i = 0; i < 8; i++) {
                if (fv[i] != 0.0f && lo == 257) lo = k0 + i;   // cndmask chain only
            }
        }
        if (lo > 256) lo = 256;
        lo_lds[l] = lo;
#pragma unroll
        for (int i = 0; i < WMAX; i++) {
            int k = lo + i;
            wc_lds[l * WSTRIDE + i] = (k <= 256) ? filters[k * NFILT + l] : 0.0f;
        }
    }

    // ---- loop-invariant twiddles ----
    const int rl = (int)(__brev((unsigned)l) >> 26);    // rev6(lane) = k1
    float cA[6], sA[6], sg[6];
#pragma unroll
    for (int j = 0; j < 6; j++) {
        const int d = 32 >> j;
        const int hi = l & d;
        float th = -2.0f * (float)M_PI * (float)(l & (d - 1)) / (float)(2 * d);
        cA[j] = hi ? cosf(th) : 1.0f;
        sA[j] = hi ? sinf(th) : 0.0f;
        sg[j] = hi ? -1.0f : 1.0f;
    }
    float br[8], bi[8];
    {
        float th = -2.0f * (float)M_PI * (float)rl * (1.0f / 512.0f);
        float c1 = cosf(th), s1 = sinf(th);
        br[0] = 1.0f; bi[0] = 0.0f; br[1] = c1; bi[1] = s1;
#pragma unroll
        for (int r = 2; r < 8; r++) {
            float pr_ = br[r - 1], pi_ = bi[r - 1];
            br[r] = pr_ * c1 - pi_ * s1;
            bi[r] = pr_ * s1 + pi_ * c1;
        }
    }
    const int Lp = (int)(__brev((unsigned)((64 - rl) & 63)) >> 26);  // conj partner lane

    __syncthreads();
    const int lo = lo_lds[l];

    const int gw = blockIdx.x * WAVES + w;
    const int totw = NBLOCKS * WAVES;          // 4096
    const int npairs = (num_frames + 1) >> 1;

    // two independent pairs (4 frames) in flight per iteration
    for (int p0 = gw; p0 < npairs; p0 += 2 * totw) {
        const int p1 = p0 + totw;
        const bool v1 = (p1 < npairs);
        const int p1c = v1 ? p1 : p0;          // clamp: duplicate work, skip stores

        const long fA = 2L * p0;
        const long fB = 2L * p1c;
        const bool hasbA = (fA + 1) < num_frames;
        const bool hasbB = (fB + 1) < num_frames;

        float vrA[8], viA[8], vrB[8], viB[8];
        load_pre(x, fA * FRAME_STEP, l, true, vrA);
        load_pre(x, (fA + 1) * FRAME_STEP, l, hasbA, viA);
        load_pre(x, fB * FRAME_STEP, l, true, vrB);
        load_pre(x, (fB + 1) * FRAME_STEP, l, hasbB, viB);

        fft512(vrA, viA, cA, sA, sg, br, bi);
        fft512(vrB, viB, cA, sA, sg, br, bi);

        untangle_power(vrA, viA, l, rl, Lp, pwA);
        untangle_power(vrB, viB, l, rl, Lp, pwB);

        asm volatile("s_waitcnt lgkmcnt(0)" ::: "memory");  // wave-local LDS fence

        // ---- sparse mel matmul, 4 frames per weight read ----
        float ac0 = 1e-30f, ac1 = 1e-30f, ac2 = 1e-30f, ac3 = 1e-30f;
#pragma unroll
        for (int i = 0; i < WMAX; i++) {
            float wv = wc_lds[l * WSTRIDE + i];
            float2 pA = *reinterpret_cast<const float2*>(&pwA[2 * (lo + i)]);
            float2 pB = *reinterpret_cast<const float2*>(&pwB[2 * (lo + i)]);
            ac0 = fmaf(wv, pA.x, ac0);
            ac1 = fmaf(wv, pA.y, ac1);
            ac2 = fmaf(wv, pB.x, ac2);
            ac3 = fmaf(wv, pB.y, ac3);
        }

        // ---- per-frame normalize: 4 independent reduction chains ----
        float s0 = ac0, s1 = ac1, s2 = ac2, s3 = ac3;
#pragma unroll
        for (int mk = 1; mk < 64; mk <<= 1) {
            s0 += __shfl_xor(s0, mk, 64);
            s1 += __shfl_xor(s1, mk, 64);
            s2 += __shfl_xor(s2, mk, 64);
            s3 += __shfl_xor(s3, mk, 64);
        }
        const float m0 = s0 * (1.0f/64.0f), m1 = s1 * (1.0f/64.0f);
        const float m2 = s2 * (1.0f/64.0f), m3 = s3 * (1.0f/64.0f);
        const float d0 = ac0 - m0, d1 = ac1 - m1, d2 = ac2 - m2, d3 = ac3 - m3;
        float q0 = d0*d0, q1 = d1*d1, q2 = d2*d2, q3 = d3*d3;
#pragma unroll
        for (int mk = 1; mk < 64; mk <<= 1) {
            q0 += __shfl_xor(q0, mk, 64);
            q1 += __shfl_xor(q1, mk, 64);
            q2 += __shfl_xor(q2, mk, 64);
            q3 += __shfl_xor(q3, mk, 64);
        }
        out[fA * NFILT + l] = d0 / sqrtf(q0 * (1.0f/64.0f));
        if (hasbA) out[(fA + 1) * NFILT + l] = d1 / sqrtf(q1 * (1.0f/64.0f));
        if (v1) {
            out[fB * NFILT + l] = d2 / sqrtf(q2 * (1.0f/64.0f));
            if (hasbB) out[(fB + 1) * NFILT + l] = d3 / sqrtf(q3 * (1.0f/64.0f));
        }
    }
}

extern "C" void kernel_launch(void* const* d_in, const int* in_sizes, int n_in,
                              void* d_out, int out_size, void* d_ws, size_t ws_size,
                              hipStream_t stream) {
    (void)d_ws; (void)ws_size; (void)n_in; (void)in_sizes;
    const float* x = (const float*)d_in[0];
    const float* filters = (const float*)d_in[1];
    float* out = (float*)d_out;
    const int num_frames = out_size / NFILT;
    fbank_kernel<<<NBLOCKS, 256, 0, stream>>>(x, filters, out, num_frames);
}